// Round 1
// baseline (1475.865 us; speedup 1.0000x reference)
//
#include <hip/hip_runtime.h>
#include <hip/hip_bf16.h>
#include <cstdint>
#include <cstddef>

#define NSRC 100000
#define NDST 50000
#define DD 128
#define DOUT 128
#define KK2 256   // 2*D

typedef __attribute__((ext_vector_type(8))) short bf16x8;
typedef __attribute__((ext_vector_type(4))) float f32x4;

static __device__ __forceinline__ unsigned short f2bf(float f) {
    union { float f; uint32_t u; } v; v.f = f;
    uint32_t u = v.u;
    uint32_t r = u + 0x7FFFu + ((u >> 16) & 1u);   // round-to-nearest-even
    return (unsigned short)(r >> 16);
}

// ---------------- K1: hdelta = H_src - HBar_src ----------------
__global__ void k_hdelta(const float4* __restrict__ a, const float4* __restrict__ b,
                         float4* __restrict__ o, int n4) {
    int i = blockIdx.x * blockDim.x + threadIdx.x;
    if (i < n4) {
        float4 x = a[i], y = b[i];
        o[i] = make_float4(x.x - y.x, x.y - y.y, x.z - y.z, x.w - y.w);
    }
}

// ---------------- K2: W^T bf16 [DOUT][K2] ----------------
__global__ void k_wt(const float* __restrict__ W, unsigned short* __restrict__ WT) {
    int i = blockIdx.x * blockDim.x + threadIdx.x;
    if (i >= DOUT * KK2) return;
    int n = i >> 8;       // output col
    int k = i & 255;      // k index
    WT[i] = f2bf(W[k * DOUT + n]);
}

// ---------------- K3: edge scatter (precomputed hdelta path) ----------------
__global__ void k_edge_hd(const float4* __restrict__ hd,
                          const int* __restrict__ src, const int* __restrict__ dst,
                          float* __restrict__ summed, float* __restrict__ deg, int E) {
    int t = blockIdx.x * blockDim.x + threadIdx.x;
    int e = t >> 5, j = t & 31;
    if (e >= E) return;
    int s = src[e], d = dst[e];
    float4 v = hd[(size_t)s * 32 + j];
    float* p = summed + (size_t)d * 128 + j * 4;
    atomicAdd(p + 0, v.x);
    atomicAdd(p + 1, v.y);
    atomicAdd(p + 2, v.z);
    atomicAdd(p + 3, v.w);
    if (j == 0) atomicAdd(deg + d, 1.0f);
}

// ---------------- K3b: edge scatter computing hdelta on the fly (small-ws fallback) ----------------
__global__ void k_edge_fly(const float4* __restrict__ hs, const float4* __restrict__ hb,
                           const int* __restrict__ src, const int* __restrict__ dst,
                           float* __restrict__ summed, float* __restrict__ deg, int E) {
    int t = blockIdx.x * blockDim.x + threadIdx.x;
    int e = t >> 5, j = t & 31;
    if (e >= E) return;
    int s = src[e], d = dst[e];
    float4 x = hs[(size_t)s * 32 + j];
    float4 y = hb[(size_t)s * 32 + j];
    float4 v = make_float4(x.x - y.x, x.y - y.y, x.z - y.z, x.w - y.w);
    float* p = summed + (size_t)d * 128 + j * 4;
    atomicAdd(p + 0, v.x);
    atomicAdd(p + 1, v.y);
    atomicAdd(p + 2, v.z);
    atomicAdd(p + 3, v.w);
    if (j == 0) atomicAdd(deg + d, 1.0f);
}

// ---------------- K4: build x_bf16 [NDST][256] = [H_dst | agg + summed/deg] ----------------
__global__ void k_buildx(const float4* __restrict__ Hd, const float4* __restrict__ agg,
                         const float4* __restrict__ summed, const float* __restrict__ deg,
                         ushort4* __restrict__ xo, int n) {
    int i = blockIdx.x * blockDim.x + threadIdx.x;
    if (i >= n) return;
    int r = i >> 6, g = i & 63;
    float4 v;
    if (g < 32) {
        v = Hd[(size_t)r * 32 + g];
    } else {
        int gg = g - 32;
        float inv = 1.0f / fmaxf(deg[r], 1.0f);
        float4 s = summed[(size_t)r * 32 + gg];
        float4 a = agg[(size_t)r * 32 + gg];
        v = make_float4(a.x + s.x * inv, a.y + s.y * inv, a.z + s.z * inv, a.w + s.w * inv);
    }
    ushort4 u;
    u.x = f2bf(v.x); u.y = f2bf(v.y); u.z = f2bf(v.z); u.w = f2bf(v.w);
    xo[i] = u;
}

// ---------------- K5: GEMM [NDST,256] x [256,128] bf16 MFMA + bias + relu ----------------
// block = 256 threads = 4 waves; block owns one 16-row M-tile; wave w owns cols [w*32, w*32+32)
__global__ __launch_bounds__(256) void k_gemm(const unsigned short* __restrict__ X,
                                              const unsigned short* __restrict__ WT,
                                              const float* __restrict__ bias,
                                              float* __restrict__ out) {
    int mt = blockIdx.x;
    int w = threadIdx.x >> 6;
    int l = threadIdx.x & 63;
    int lr = l & 15, lg = l >> 4;

    const bf16x8* A  = reinterpret_cast<const bf16x8*>(X  + (size_t)(mt * 16 + lr) * KK2 + lg * 8);
    const bf16x8* B0 = reinterpret_cast<const bf16x8*>(WT + (size_t)(w * 32 + lr) * KK2 + lg * 8);
    const bf16x8* B1 = reinterpret_cast<const bf16x8*>(WT + (size_t)(w * 32 + 16 + lr) * KK2 + lg * 8);

    f32x4 acc0 = {0.f, 0.f, 0.f, 0.f};
    f32x4 acc1 = {0.f, 0.f, 0.f, 0.f};
#pragma unroll
    for (int kk = 0; kk < 8; ++kk) {
        bf16x8 a  = A[kk * 4];    // advance 32 bf16 = 4 * 16B
        bf16x8 b0 = B0[kk * 4];
        bf16x8 b1 = B1[kk * 4];
        acc0 = __builtin_amdgcn_mfma_f32_16x16x32_bf16(a, b0, acc0, 0, 0, 0);
        acc1 = __builtin_amdgcn_mfma_f32_16x16x32_bf16(a, b1, acc1, 0, 0, 0);
    }

    int col0 = w * 32 + lr;
    int col1 = col0 + 16;
    float bi0 = bias[col0], bi1 = bias[col1];
    int rowb = mt * 16 + lg * 4;
#pragma unroll
    for (int j = 0; j < 4; ++j) {
        float v0 = acc0[j] + bi0;
        float v1 = acc1[j] + bi1;
        out[(size_t)(rowb + j) * DOUT + col0] = v0 > 0.f ? v0 : 0.f;
        out[(size_t)(rowb + j) * DOUT + col1] = v1 > 0.f ? v1 : 0.f;
    }
}

extern "C" void kernel_launch(void* const* d_in, const int* in_sizes, int n_in,
                              void* d_out, int out_size, void* d_ws, size_t ws_size,
                              hipStream_t stream) {
    const float* H_src    = (const float*)d_in[0];
    const float* H_dst    = (const float*)d_in[1];
    const float* HBar_src = (const float*)d_in[2];
    const float* agg      = (const float*)d_in[3];
    const float* W        = (const float*)d_in[4];
    const float* bias     = (const float*)d_in[5];
    const int*   src      = (const int*)d_in[6];
    const int*   dst      = (const int*)d_in[7];
    float* out = (float*)d_out;
    const int E = in_sizes[6];

    // ws layout (byte offsets, 512-aligned):
    //   summed : 0          .. 25,600,000   (NDST*128 f32)
    //   deg    : 25,600,000 .. 25,800,000   (NDST f32)
    //   WT     : 25,800,192 .. 25,865,728   (128*256 bf16)
    //   X      : 25,865,728 .. 51,465,728   (NDST*256 bf16)
    //   hdelta : 51,465,728 .. 102,665,728  (NSRC*128 f32, optional)
    char* ws = (char*)d_ws;
    float* summed          = (float*)ws;
    float* deg             = (float*)(ws + 25600000);
    unsigned short* WT     = (unsigned short*)(ws + 25800192);
    unsigned short* X      = (unsigned short*)(ws + 25865728);
    float* hdelta          = (float*)(ws + 51465728);
    bool use_hd = (ws_size >= 102665728ull);

    // zero the accumulators (summed + deg)
    hipMemsetAsync(ws, 0, 25800000, stream);

    k_wt<<<(DOUT * KK2 + 255) / 256, 256, 0, stream>>>(W, WT);

    if (use_hd) {
        int n4 = NSRC * 32;
        k_hdelta<<<(n4 + 255) / 256, 256, 0, stream>>>(
            (const float4*)H_src, (const float4*)HBar_src, (float4*)hdelta, n4);
        int nt = E * 32;
        k_edge_hd<<<(nt + 255) / 256, 256, 0, stream>>>(
            (const float4*)hdelta, src, dst, summed, deg, E);
    } else {
        int nt = E * 32;
        k_edge_fly<<<(nt + 255) / 256, 256, 0, stream>>>(
            (const float4*)H_src, (const float4*)HBar_src, src, dst, summed, deg, E);
    }

    int nx = NDST * 64;
    k_buildx<<<(nx + 255) / 256, 256, 0, stream>>>(
        (const float4*)H_dst, (const float4*)agg, (const float4*)summed, deg,
        (ushort4*)X, nx);

    k_gemm<<<NDST / 16, 256, 0, stream>>>(X, WT, bias, out);
}

// Round 2
// 273.766 us; speedup vs baseline: 5.3910x; 5.3910x over previous
//
#include <hip/hip_runtime.h>
#include <hip/hip_bf16.h>
#include <cstdint>
#include <cstddef>

#define NSRC 100000
#define NDST 50000
#define DD 128
#define DOUT 128
#define KK2 256   // 2*D

typedef __attribute__((ext_vector_type(8))) short bf16x8;
typedef __attribute__((ext_vector_type(4))) float f32x4;

static __device__ __forceinline__ unsigned short f2bf(float f) {
    union { float f; uint32_t u; } v; v.f = f;
    uint32_t u = v.u;
    uint32_t r = u + 0x7FFFu + ((u >> 16) & 1u);   // round-to-nearest-even
    return (unsigned short)(r >> 16);
}

// ---------------- K1: hdelta = H_src - HBar_src ----------------
__global__ void k_hdelta(const float4* __restrict__ a, const float4* __restrict__ b,
                         float4* __restrict__ o, int n4) {
    int i = blockIdx.x * blockDim.x + threadIdx.x;
    if (i < n4) {
        float4 x = a[i], y = b[i];
        o[i] = make_float4(x.x - y.x, x.y - y.y, x.z - y.z, x.w - y.w);
    }
}

// ---------------- K2: W^T bf16 [DOUT][K2] ----------------
__global__ void k_wt(const float* __restrict__ W, unsigned short* __restrict__ WT) {
    int i = blockIdx.x * blockDim.x + threadIdx.x;
    if (i >= DOUT * KK2) return;
    int n = i >> 8;       // output col
    int k = i & 255;      // k index
    WT[i] = f2bf(W[k * DOUT + n]);
}

// ---------------- K3: histogram of dst ----------------
__global__ void k_hist(const int* __restrict__ dst, int* __restrict__ cnt, int E) {
    int e = blockIdx.x * blockDim.x + threadIdx.x;
    if (e < E) atomicAdd(&cnt[dst[e]], 1);
}

// ---------------- K4: exclusive scan of cnt[n] -> off[n+1], single block ----------------
__global__ __launch_bounds__(1024) void k_scan(const int* __restrict__ cnt,
                                               int* __restrict__ off, int n) {
    __shared__ int wsum[16];
    __shared__ int wexcl[16];
    __shared__ int total_s;
    __shared__ int carry_s;
    int lane = threadIdx.x & 63, w = threadIdx.x >> 6;
    if (threadIdx.x == 0) carry_s = 0;
    __syncthreads();
    for (int base = 0; base < n; base += 1024) {
        int i = base + threadIdx.x;
        int v = (i < n) ? cnt[i] : 0;
        int x = v;
#pragma unroll
        for (int s = 1; s < 64; s <<= 1) {
            int t = __shfl_up(x, s, 64);
            if (lane >= s) x += t;
        }
        if (lane == 63) wsum[w] = x;
        __syncthreads();
        if (threadIdx.x < 16) {
            int orig = wsum[threadIdx.x];
            int y = orig;
#pragma unroll
            for (int s = 1; s < 16; s <<= 1) {
                int t = __shfl_up(y, s, 16);
                if ((int)threadIdx.x >= s) y += t;
            }
            wexcl[threadIdx.x] = y - orig;
            if (threadIdx.x == 15) total_s = y;
        }
        __syncthreads();
        if (i < n) off[i] = carry_s + wexcl[w] + (x - v);
        __syncthreads();
        if (threadIdx.x == 0) carry_s += total_s;
        __syncthreads();
    }
    if (threadIdx.x == 0) off[n] = carry_s;
}

// ---------------- K5: scatter src ids into dst-sorted buckets ----------------
__global__ void k_scatter(const int* __restrict__ src, const int* __restrict__ dst,
                          const int* __restrict__ off, int* __restrict__ cur,
                          int* __restrict__ idx, int E) {
    int e = blockIdx.x * blockDim.x + threadIdx.x;
    if (e < E) {
        int d = dst[e];
        int p = off[d] + atomicAdd(&cur[d], 1);
        idx[p] = src[e];
    }
}

// ---------------- K6: per-dst gather-sum + mean + agg + bf16 X build ----------------
// one wave per dst row; lane owns float2 slice (2 cols)
__global__ __launch_bounds__(256) void k_gather(const float2* __restrict__ hd,
                                                const float2* __restrict__ Hd,
                                                const float2* __restrict__ agg,
                                                const int* __restrict__ off,
                                                const int* __restrict__ idx,
                                                ushort2* __restrict__ X, int n) {
    int r = blockIdx.x * 4 + (threadIdx.x >> 6);
    if (r >= n) return;
    int lane = threadIdx.x & 63;
    int o0 = off[r], o1 = off[r + 1];
    float accx = 0.f, accy = 0.f;
    int e = o0;
    // unroll-by-2 to overlap gather latency
    for (; e + 1 < o1; e += 2) {
        int s0 = idx[e], s1 = idx[e + 1];
        float2 v0 = hd[(size_t)s0 * 64 + lane];
        float2 v1 = hd[(size_t)s1 * 64 + lane];
        accx += v0.x + v1.x;
        accy += v0.y + v1.y;
    }
    if (e < o1) {
        int s0 = idx[e];
        float2 v0 = hd[(size_t)s0 * 64 + lane];
        accx += v0.x;
        accy += v0.y;
    }
    float inv = 1.0f / fmaxf((float)(o1 - o0), 1.0f);
    float2 a = agg[(size_t)r * 64 + lane];
    float2 hdst = Hd[(size_t)r * 64 + lane];
    ushort2 u0 = make_ushort2(f2bf(hdst.x), f2bf(hdst.y));
    ushort2 u1 = make_ushort2(f2bf(a.x + accx * inv), f2bf(a.y + accy * inv));
    X[(size_t)r * 128 + lane] = u0;        // cols [0,128): H_dst
    X[(size_t)r * 128 + 64 + lane] = u1;   // cols [128,256): h_neigh
}

// ---------------- K7: GEMM [NDST,256] x [256,128] bf16 MFMA + bias + relu ----------------
__global__ __launch_bounds__(256) void k_gemm(const unsigned short* __restrict__ X,
                                              const unsigned short* __restrict__ WT,
                                              const float* __restrict__ bias,
                                              float* __restrict__ out) {
    int mt = blockIdx.x;
    int w = threadIdx.x >> 6;
    int l = threadIdx.x & 63;
    int lr = l & 15, lg = l >> 4;

    const bf16x8* A  = reinterpret_cast<const bf16x8*>(X  + (size_t)(mt * 16 + lr) * KK2 + lg * 8);
    const bf16x8* B0 = reinterpret_cast<const bf16x8*>(WT + (size_t)(w * 32 + lr) * KK2 + lg * 8);
    const bf16x8* B1 = reinterpret_cast<const bf16x8*>(WT + (size_t)(w * 32 + 16 + lr) * KK2 + lg * 8);

    f32x4 acc0 = {0.f, 0.f, 0.f, 0.f};
    f32x4 acc1 = {0.f, 0.f, 0.f, 0.f};
#pragma unroll
    for (int kk = 0; kk < 8; ++kk) {
        bf16x8 a  = A[kk * 4];
        bf16x8 b0 = B0[kk * 4];
        bf16x8 b1 = B1[kk * 4];
        acc0 = __builtin_amdgcn_mfma_f32_16x16x32_bf16(a, b0, acc0, 0, 0, 0);
        acc1 = __builtin_amdgcn_mfma_f32_16x16x32_bf16(a, b1, acc1, 0, 0, 0);
    }

    int col0 = w * 32 + lr;
    int col1 = col0 + 16;
    float bi0 = bias[col0], bi1 = bias[col1];
    int rowb = mt * 16 + lg * 4;
#pragma unroll
    for (int j = 0; j < 4; ++j) {
        float v0 = acc0[j] + bi0;
        float v1 = acc1[j] + bi1;
        out[(size_t)(rowb + j) * DOUT + col0] = v0 > 0.f ? v0 : 0.f;
        out[(size_t)(rowb + j) * DOUT + col1] = v1 > 0.f ? v1 : 0.f;
    }
}

extern "C" void kernel_launch(void* const* d_in, const int* in_sizes, int n_in,
                              void* d_out, int out_size, void* d_ws, size_t ws_size,
                              hipStream_t stream) {
    const float* H_src    = (const float*)d_in[0];
    const float* H_dst    = (const float*)d_in[1];
    const float* HBar_src = (const float*)d_in[2];
    const float* agg      = (const float*)d_in[3];
    const float* W        = (const float*)d_in[4];
    const float* bias     = (const float*)d_in[5];
    const int*   src      = (const int*)d_in[6];
    const int*   dst      = (const int*)d_in[7];
    float* out = (float*)d_out;
    const int E = in_sizes[6];

    // ws layout (byte offsets, 512-aligned):
    //   cnt        : 0         .. 200,000    (NDST i32)
    //   cnt2       : 200,192   .. 400,192    (NDST i32)
    //   off        : 400,384   .. 600,388    (NDST+1 i32)
    //   idx_sorted : 600,576   .. 3,800,576  (E i32)
    //   WT         : 3,800,576 .. 3,866,112  (128*256 bf16)
    //   X          : 3,866,112 .. 29,466,112 (NDST*256 bf16)
    //   hdelta     : 29,466,112.. 80,666,112 (NSRC*128 f32)
    char* ws = (char*)d_ws;
    int* cnt             = (int*)ws;
    int* cnt2            = (int*)(ws + 200192);
    int* off             = (int*)(ws + 400384);
    int* idx_sorted      = (int*)(ws + 600576);
    unsigned short* WT   = (unsigned short*)(ws + 3800576);
    unsigned short* X    = (unsigned short*)(ws + 3866112);
    float* hdelta        = (float*)(ws + 29466112);

    // zero cnt + cnt2
    hipMemsetAsync(ws, 0, 400384, stream);

    k_wt<<<(DOUT * KK2 + 255) / 256, 256, 0, stream>>>(W, WT);

    int n4 = NSRC * 32;
    k_hdelta<<<(n4 + 255) / 256, 256, 0, stream>>>(
        (const float4*)H_src, (const float4*)HBar_src, (float4*)hdelta, n4);

    k_hist<<<(E + 255) / 256, 256, 0, stream>>>(dst, cnt, E);

    k_scan<<<1, 1024, 0, stream>>>(cnt, off, NDST);

    k_scatter<<<(E + 255) / 256, 256, 0, stream>>>(src, dst, off, cnt2, idx_sorted, E);

    k_gather<<<(NDST + 3) / 4, 256, 0, stream>>>(
        (const float2*)hdelta, (const float2*)H_dst, (const float2*)agg,
        off, idx_sorted, (ushort2*)X, NDST);

    k_gemm<<<NDST / 16, 256, 0, stream>>>(X, WT, bias, out);
}

// Round 3
// 202.843 us; speedup vs baseline: 7.2759x; 1.3496x over previous
//
#include <hip/hip_runtime.h>
#include <hip/hip_bf16.h>
#include <cstdint>
#include <cstddef>

#define NSRC 100000
#define NDST 50000
#define DOUT 128
#define KK2 256   // 2*D

typedef __attribute__((ext_vector_type(8))) short bf16x8;
typedef __attribute__((ext_vector_type(4))) float f32x4;

static __device__ __forceinline__ unsigned short f2bf(float f) {
    union { float f; uint32_t u; } v; v.f = f;
    uint32_t u = v.u;
    uint32_t r = u + 0x7FFFu + ((u >> 16) & 1u);   // round-to-nearest-even
    return (unsigned short)(r >> 16);
}
static __device__ __forceinline__ float bf_lo(uint32_t u) {
    union { uint32_t x; float f; } v; v.x = u << 16; return v.f;
}
static __device__ __forceinline__ float bf_hi(uint32_t u) {
    union { uint32_t x; float f; } v; v.x = u & 0xFFFF0000u; return v.f;
}

// ---------------- K1: hdelta_bf16 = bf16(H_src - HBar_src) ----------------
__global__ void k_hdelta_bf(const float4* __restrict__ a, const float4* __restrict__ b,
                            ushort4* __restrict__ o, int n4) {
    int i = blockIdx.x * blockDim.x + threadIdx.x;
    if (i < n4) {
        float4 x = a[i], y = b[i];
        ushort4 u;
        u.x = f2bf(x.x - y.x); u.y = f2bf(x.y - y.y);
        u.z = f2bf(x.z - y.z); u.w = f2bf(x.w - y.w);
        o[i] = u;
    }
}

// ---------------- K2: W^T bf16 [DOUT][K2] ----------------
__global__ void k_wt(const float* __restrict__ W, unsigned short* __restrict__ WT) {
    int i = blockIdx.x * blockDim.x + threadIdx.x;
    if (i >= DOUT * KK2) return;
    int n = i >> 8;
    int k = i & 255;
    WT[i] = f2bf(W[k * DOUT + n]);
}

// ---------------- K3: histogram of dst ----------------
__global__ void k_hist(const int* __restrict__ dst, int* __restrict__ cnt, int E) {
    int e = blockIdx.x * blockDim.x + threadIdx.x;
    if (e < E) atomicAdd(&cnt[dst[e]], 1);
}

// ---------------- K4a: per-block sums ----------------
__global__ __launch_bounds__(256) void k_scan1(const int* __restrict__ cnt,
                                               int* __restrict__ bsum, int n) {
    int i = blockIdx.x * 256 + threadIdx.x;
    int v = (i < n) ? cnt[i] : 0;
#pragma unroll
    for (int s = 1; s < 64; s <<= 1) v += __shfl_xor(v, s, 64);
    __shared__ int wsum[4];
    if ((threadIdx.x & 63) == 0) wsum[threadIdx.x >> 6] = v;
    __syncthreads();
    if (threadIdx.x == 0) bsum[blockIdx.x] = wsum[0] + wsum[1] + wsum[2] + wsum[3];
}

// ---------------- K4b: single-block scan of block sums (nb <= 256) ----------------
__global__ __launch_bounds__(256) void k_scan2(const int* __restrict__ bsum,
                                               int* __restrict__ bexcl,
                                               int* __restrict__ off_last, int nb) {
    int i = threadIdx.x;
    int v = (i < nb) ? bsum[i] : 0;
    int lane = i & 63, w = i >> 6;
    int x = v;
#pragma unroll
    for (int s = 1; s < 64; s <<= 1) { int t = __shfl_up(x, s, 64); if (lane >= s) x += t; }
    __shared__ int wsum[4], wex[4], total_s;
    if (lane == 63) wsum[w] = x;
    __syncthreads();
    if (threadIdx.x == 0) {
        int run = 0;
#pragma unroll
        for (int k = 0; k < 4; ++k) { wex[k] = run; run += wsum[k]; }
        total_s = run;
    }
    __syncthreads();
    if (i < nb) bexcl[i] = wex[w] + x - v;
    if (i == 0) *off_last = total_s;
}

// ---------------- K4c: apply — exclusive scan result ----------------
__global__ __launch_bounds__(256) void k_scan3(const int* __restrict__ cnt,
                                               const int* __restrict__ bexcl,
                                               int* __restrict__ off, int n) {
    int i = blockIdx.x * 256 + threadIdx.x;
    int v = (i < n) ? cnt[i] : 0;
    int lane = threadIdx.x & 63, w = threadIdx.x >> 6;
    int x = v;
#pragma unroll
    for (int s = 1; s < 64; s <<= 1) { int t = __shfl_up(x, s, 64); if (lane >= s) x += t; }
    __shared__ int wsum[4], wex[4];
    if (lane == 63) wsum[w] = x;
    __syncthreads();
    if (threadIdx.x == 0) {
        int run = 0;
#pragma unroll
        for (int k = 0; k < 4; ++k) { wex[k] = run; run += wsum[k]; }
    }
    __syncthreads();
    if (i < n) off[i] = bexcl[blockIdx.x] + wex[w] + x - v;
}

// ---------------- K5: scatter src ids into dst-sorted buckets ----------------
__global__ void k_scatter(const int* __restrict__ src, const int* __restrict__ dst,
                          const int* __restrict__ off, int* __restrict__ cur,
                          int* __restrict__ idx, int E) {
    int e = blockIdx.x * blockDim.x + threadIdx.x;
    if (e < E) {
        int d = dst[e];
        int p = off[d] + atomicAdd(&cur[d], 1);
        idx[p] = src[e];
    }
}

// ---------------- K6: per-dst gather-sum (bf16 rows) + mean + agg + X build ----------------
// one wave per dst row; lane owns 2 cols (one uint = 2 bf16)
__global__ __launch_bounds__(256) void k_gather(const uint32_t* __restrict__ hd,
                                                const float2* __restrict__ Hd,
                                                const float2* __restrict__ agg,
                                                const int* __restrict__ off,
                                                const int* __restrict__ idx,
                                                ushort2* __restrict__ X, int n) {
    int r = blockIdx.x * 4 + (threadIdx.x >> 6);
    if (r >= n) return;
    int lane = threadIdx.x & 63;
    int o0 = off[r], o1 = off[r + 1];
    float accx = 0.f, accy = 0.f;
    int e = o0;
    for (; e + 3 < o1; e += 4) {
        int s0 = idx[e], s1 = idx[e + 1], s2 = idx[e + 2], s3 = idx[e + 3];
        uint32_t v0 = hd[(size_t)s0 * 64 + lane];
        uint32_t v1 = hd[(size_t)s1 * 64 + lane];
        uint32_t v2 = hd[(size_t)s2 * 64 + lane];
        uint32_t v3 = hd[(size_t)s3 * 64 + lane];
        accx += bf_lo(v0) + bf_lo(v1) + bf_lo(v2) + bf_lo(v3);
        accy += bf_hi(v0) + bf_hi(v1) + bf_hi(v2) + bf_hi(v3);
    }
    for (; e < o1; ++e) {
        uint32_t v0 = hd[(size_t)idx[e] * 64 + lane];
        accx += bf_lo(v0);
        accy += bf_hi(v0);
    }
    float inv = 1.0f / fmaxf((float)(o1 - o0), 1.0f);
    float2 a = agg[(size_t)r * 64 + lane];
    float2 hdst = Hd[(size_t)r * 64 + lane];
    ushort2 u0 = make_ushort2(f2bf(hdst.x), f2bf(hdst.y));
    ushort2 u1 = make_ushort2(f2bf(a.x + accx * inv), f2bf(a.y + accy * inv));
    X[(size_t)r * 128 + lane] = u0;        // cols [0,128): H_dst
    X[(size_t)r * 128 + 64 + lane] = u1;   // cols [128,256): h_neigh
}

// ---------------- K7: GEMM [NDST,256] x [256,128] bf16 MFMA + bias + relu ----------------
__global__ __launch_bounds__(256) void k_gemm(const unsigned short* __restrict__ X,
                                              const unsigned short* __restrict__ WT,
                                              const float* __restrict__ bias,
                                              float* __restrict__ out) {
    int mt = blockIdx.x;
    int w = threadIdx.x >> 6;
    int l = threadIdx.x & 63;
    int lr = l & 15, lg = l >> 4;

    const bf16x8* A  = reinterpret_cast<const bf16x8*>(X  + (size_t)(mt * 16 + lr) * KK2 + lg * 8);
    const bf16x8* B0 = reinterpret_cast<const bf16x8*>(WT + (size_t)(w * 32 + lr) * KK2 + lg * 8);
    const bf16x8* B1 = reinterpret_cast<const bf16x8*>(WT + (size_t)(w * 32 + 16 + lr) * KK2 + lg * 8);

    f32x4 acc0 = {0.f, 0.f, 0.f, 0.f};
    f32x4 acc1 = {0.f, 0.f, 0.f, 0.f};
#pragma unroll
    for (int kk = 0; kk < 8; ++kk) {
        bf16x8 a  = A[kk * 4];
        bf16x8 b0 = B0[kk * 4];
        bf16x8 b1 = B1[kk * 4];
        acc0 = __builtin_amdgcn_mfma_f32_16x16x32_bf16(a, b0, acc0, 0, 0, 0);
        acc1 = __builtin_amdgcn_mfma_f32_16x16x32_bf16(a, b1, acc1, 0, 0, 0);
    }

    int col0 = w * 32 + lr;
    int col1 = col0 + 16;
    float bi0 = bias[col0], bi1 = bias[col1];
    int rowb = mt * 16 + lg * 4;
#pragma unroll
    for (int j = 0; j < 4; ++j) {
        float v0 = acc0[j] + bi0;
        float v1 = acc1[j] + bi1;
        out[(size_t)(rowb + j) * DOUT + col0] = v0 > 0.f ? v0 : 0.f;
        out[(size_t)(rowb + j) * DOUT + col1] = v1 > 0.f ? v1 : 0.f;
    }
}

extern "C" void kernel_launch(void* const* d_in, const int* in_sizes, int n_in,
                              void* d_out, int out_size, void* d_ws, size_t ws_size,
                              hipStream_t stream) {
    const float* H_src    = (const float*)d_in[0];
    const float* H_dst    = (const float*)d_in[1];
    const float* HBar_src = (const float*)d_in[2];
    const float* agg      = (const float*)d_in[3];
    const float* W        = (const float*)d_in[4];
    const float* bias     = (const float*)d_in[5];
    const int*   src      = (const int*)d_in[6];
    const int*   dst      = (const int*)d_in[7];
    float* out = (float*)d_out;
    const int E = in_sizes[6];
    const int NB = (NDST + 255) / 256;   // 196

    // ws layout (byte offsets, 512-aligned):
    //   cnt    : 0         .. 200,000
    //   cnt2   : 200,192   .. 400,192
    //   off    : 400,384   .. 600,388   (NDST+1)
    //   bsum   : 600,576   .. 601,360   (196 i32)
    //   bexcl  : 601,600   .. 602,384
    //   idx    : 602,624   .. 3,802,624 (E i32)
    //   WT     : 3,803,136 .. 3,868,672 (128*256 bf16)
    //   X      : 3,868,672 .. 29,468,672 (NDST*256 bf16)
    //   hd_bf  : 29,468,672.. 55,068,672 (NSRC*128 bf16)
    char* ws = (char*)d_ws;
    int* cnt             = (int*)ws;
    int* cnt2            = (int*)(ws + 200192);
    int* off             = (int*)(ws + 400384);
    int* bsum            = (int*)(ws + 600576);
    int* bexcl           = (int*)(ws + 601600);
    int* idx_sorted      = (int*)(ws + 602624);
    unsigned short* WT   = (unsigned short*)(ws + 3803136);
    unsigned short* X    = (unsigned short*)(ws + 3868672);
    unsigned short* hdbf = (unsigned short*)(ws + 29468672);

    hipMemsetAsync(ws, 0, 400384, stream);   // cnt + cnt2

    k_wt<<<(DOUT * KK2 + 255) / 256, 256, 0, stream>>>(W, WT);

    int n4 = NSRC * 32;
    k_hdelta_bf<<<(n4 + 255) / 256, 256, 0, stream>>>(
        (const float4*)H_src, (const float4*)HBar_src, (ushort4*)hdbf, n4);

    k_hist<<<(E + 255) / 256, 256, 0, stream>>>(dst, cnt, E);

    k_scan1<<<NB, 256, 0, stream>>>(cnt, bsum, NDST);
    k_scan2<<<1, 256, 0, stream>>>(bsum, bexcl, off + NDST, NB);
    k_scan3<<<NB, 256, 0, stream>>>(cnt, bexcl, off, NDST);

    k_scatter<<<(E + 255) / 256, 256, 0, stream>>>(src, dst, off, cnt2, idx_sorted, E);

    k_gather<<<(NDST + 3) / 4, 256, 0, stream>>>(
        (const uint32_t*)hdbf, (const float2*)H_dst, (const float2*)agg,
        off, idx_sorted, (ushort2*)X, NDST);

    k_gemm<<<NDST / 16, 256, 0, stream>>>(X, WT, bias, out);
}

// Round 4
// 170.634 us; speedup vs baseline: 8.6493x; 1.1888x over previous
//
#include <hip/hip_runtime.h>
#include <hip/hip_bf16.h>
#include <cstdint>
#include <cstddef>

#define NSRC 100000
#define NDST 50000
#define DOUT 128
#define KK2 256   // 2*D

typedef __attribute__((ext_vector_type(8))) short bf16x8;
typedef __attribute__((ext_vector_type(4))) float f32x4;

static __device__ __forceinline__ unsigned short f2bf(float f) {
    union { float f; uint32_t u; } v; v.f = f;
    uint32_t u = v.u;
    uint32_t r = u + 0x7FFFu + ((u >> 16) & 1u);   // round-to-nearest-even
    return (unsigned short)(r >> 16);
}
static __device__ __forceinline__ float bf_lo(uint32_t u) {
    union { uint32_t x; float f; } v; v.x = u << 16; return v.f;
}
static __device__ __forceinline__ float bf_hi(uint32_t u) {
    union { uint32_t x; float f; } v; v.x = u & 0xFFFF0000u; return v.f;
}

// ---------------- K1: prep — WT bf16 convert + zero counters ----------------
__global__ __launch_bounds__(256) void k_prep(const float* __restrict__ W,
                                              unsigned short* __restrict__ WT,
                                              int* __restrict__ cnt,
                                              int* __restrict__ cnt2) {
    int i = blockIdx.x * 256 + threadIdx.x;
    if (i < DOUT * KK2) {
        int n = i >> 8;    // output col
        int k = i & 255;   // k index
        WT[i] = f2bf(W[k * DOUT + n]);
    }
    if (i < NDST) { cnt[i] = 0; cnt2[i] = 0; }
}

// ---------------- K2: hdelta_bf16 = bf16(H_src - HBar_src), fused dst histogram ----------------
__global__ __launch_bounds__(256) void k_hd_hist(const float4* __restrict__ a,
                                                 const float4* __restrict__ b,
                                                 ushort4* __restrict__ o,
                                                 const int* __restrict__ dst,
                                                 int* __restrict__ cnt,
                                                 int E, int n4) {
    int i = blockIdx.x * 256 + threadIdx.x;
    if (i < E) atomicAdd(&cnt[dst[i]], 1);   // fire-and-forget, hides under streaming
    if (i < n4) {
        float4 x = a[i], y = b[i];
        ushort4 u;
        u.x = f2bf(x.x - y.x); u.y = f2bf(x.y - y.y);
        u.z = f2bf(x.z - y.z); u.w = f2bf(x.w - y.w);
        o[i] = u;
    }
}

// ---------------- K3a: per-block sums ----------------
__global__ __launch_bounds__(256) void k_scan1(const int* __restrict__ cnt,
                                               int* __restrict__ bsum, int n) {
    int i = blockIdx.x * 256 + threadIdx.x;
    int v = (i < n) ? cnt[i] : 0;
#pragma unroll
    for (int s = 1; s < 64; s <<= 1) v += __shfl_xor(v, s, 64);
    __shared__ int wsum[4];
    if ((threadIdx.x & 63) == 0) wsum[threadIdx.x >> 6] = v;
    __syncthreads();
    if (threadIdx.x == 0) bsum[blockIdx.x] = wsum[0] + wsum[1] + wsum[2] + wsum[3];
}

// ---------------- K3b: single-block scan of block sums (nb <= 256) ----------------
__global__ __launch_bounds__(256) void k_scan2(const int* __restrict__ bsum,
                                               int* __restrict__ bexcl,
                                               int* __restrict__ off_last, int nb) {
    int i = threadIdx.x;
    int v = (i < nb) ? bsum[i] : 0;
    int lane = i & 63, w = i >> 6;
    int x = v;
#pragma unroll
    for (int s = 1; s < 64; s <<= 1) { int t = __shfl_up(x, s, 64); if (lane >= s) x += t; }
    __shared__ int wsum[4], wex[4], total_s;
    if (lane == 63) wsum[w] = x;
    __syncthreads();
    if (threadIdx.x == 0) {
        int run = 0;
#pragma unroll
        for (int k = 0; k < 4; ++k) { wex[k] = run; run += wsum[k]; }
        total_s = run;
    }
    __syncthreads();
    if (i < nb) bexcl[i] = wex[w] + x - v;
    if (i == 0) *off_last = total_s;
}

// ---------------- K3c: apply — exclusive scan result ----------------
__global__ __launch_bounds__(256) void k_scan3(const int* __restrict__ cnt,
                                               const int* __restrict__ bexcl,
                                               int* __restrict__ off, int n) {
    int i = blockIdx.x * 256 + threadIdx.x;
    int v = (i < n) ? cnt[i] : 0;
    int lane = threadIdx.x & 63, w = threadIdx.x >> 6;
    int x = v;
#pragma unroll
    for (int s = 1; s < 64; s <<= 1) { int t = __shfl_up(x, s, 64); if (lane >= s) x += t; }
    __shared__ int wsum[4], wex[4];
    if (lane == 63) wsum[w] = x;
    __syncthreads();
    if (threadIdx.x == 0) {
        int run = 0;
#pragma unroll
        for (int k = 0; k < 4; ++k) { wex[k] = run; run += wsum[k]; }
    }
    __syncthreads();
    if (i < n) off[i] = bexcl[blockIdx.x] + wex[w] + x - v;
}

// ---------------- K4: scatter src ids into dst-sorted buckets ----------------
__global__ void k_scatter(const int* __restrict__ src, const int* __restrict__ dst,
                          const int* __restrict__ off, int* __restrict__ cur,
                          int* __restrict__ idx, int E) {
    int e = blockIdx.x * blockDim.x + threadIdx.x;
    if (e < E) {
        int d = dst[e];
        int p = off[d] + atomicAdd(&cur[d], 1);
        idx[p] = src[e];
    }
}

// ---------------- K5: fused gather-mean-agg + GEMM + bias + relu ----------------
// block = 256 thr = 4 waves, owns 16 dst rows.
// phase 1: wave w gathers rows w*4..w*4+3 (lane owns 2 cols), builds bf16 x-tile in LDS.
// phase 2: wave w computes cols [w*32, w*32+32) of the 16x128 output via MFMA.
// LDS row stride 264 shorts (528 B): row-to-row bank shift 4 -> uniform 8/bank b128 reads.
__global__ __launch_bounds__(256) void k_fused(const uint32_t* __restrict__ hd,
                                               const float2* __restrict__ Hd,
                                               const float2* __restrict__ agg,
                                               const int* __restrict__ off,
                                               const int* __restrict__ idx,
                                               const unsigned short* __restrict__ WT,
                                               const float* __restrict__ bias,
                                               float* __restrict__ out) {
    __shared__ __align__(16) unsigned short xt[16][264];
    int r0 = blockIdx.x * 16;
    int w = threadIdx.x >> 6, lane = threadIdx.x & 63;

    // ---- phase 1: gather + mean + agg -> LDS x-tile ----
#pragma unroll
    for (int q = 0; q < 4; ++q) {
        int rt = w * 4 + q;
        int r = r0 + rt;
        int o0 = off[r], o1 = off[r + 1];
        float accx = 0.f, accy = 0.f;
        int e = o0;
        for (; e + 3 < o1; e += 4) {
            int s0 = idx[e], s1 = idx[e + 1], s2 = idx[e + 2], s3 = idx[e + 3];
            uint32_t v0 = hd[(size_t)s0 * 64 + lane];
            uint32_t v1 = hd[(size_t)s1 * 64 + lane];
            uint32_t v2 = hd[(size_t)s2 * 64 + lane];
            uint32_t v3 = hd[(size_t)s3 * 64 + lane];
            accx += bf_lo(v0) + bf_lo(v1) + bf_lo(v2) + bf_lo(v3);
            accy += bf_hi(v0) + bf_hi(v1) + bf_hi(v2) + bf_hi(v3);
        }
        for (; e < o1; ++e) {
            uint32_t v0 = hd[(size_t)idx[e] * 64 + lane];
            accx += bf_lo(v0);
            accy += bf_hi(v0);
        }
        float inv = 1.0f / fmaxf((float)(o1 - o0), 1.0f);
        float2 a2 = agg[(size_t)r * 64 + lane];
        float2 hdst = Hd[(size_t)r * 64 + lane];
        *(ushort2*)&xt[rt][2 * lane]       = make_ushort2(f2bf(hdst.x), f2bf(hdst.y));
        *(ushort2*)&xt[rt][128 + 2 * lane] = make_ushort2(f2bf(a2.x + accx * inv),
                                                          f2bf(a2.y + accy * inv));
    }
    __syncthreads();

    // ---- phase 2: 16x128 GEMM tile, K=256 ----
    int lr = lane & 15, lg = lane >> 4;
    const bf16x8* B0 = reinterpret_cast<const bf16x8*>(WT + (size_t)(w * 32 + lr) * KK2 + lg * 8);
    const bf16x8* B1 = reinterpret_cast<const bf16x8*>(WT + (size_t)(w * 32 + 16 + lr) * KK2 + lg * 8);

    f32x4 acc0 = {0.f, 0.f, 0.f, 0.f};
    f32x4 acc1 = {0.f, 0.f, 0.f, 0.f};
#pragma unroll
    for (int kk = 0; kk < 8; ++kk) {
        bf16x8 av = *reinterpret_cast<const bf16x8*>(&xt[lr][lg * 8 + kk * 32]);
        acc0 = __builtin_amdgcn_mfma_f32_16x16x32_bf16(av, B0[kk * 4], acc0, 0, 0, 0);
        acc1 = __builtin_amdgcn_mfma_f32_16x16x32_bf16(av, B1[kk * 4], acc1, 0, 0, 0);
    }

    int col0 = w * 32 + lr;
    int col1 = col0 + 16;
    float bi0 = bias[col0], bi1 = bias[col1];
    int rowb = r0 + lg * 4;
#pragma unroll
    for (int j = 0; j < 4; ++j) {
        float v0 = acc0[j] + bi0;
        float v1 = acc1[j] + bi1;
        out[(size_t)(rowb + j) * DOUT + col0] = v0 > 0.f ? v0 : 0.f;
        out[(size_t)(rowb + j) * DOUT + col1] = v1 > 0.f ? v1 : 0.f;
    }
}

extern "C" void kernel_launch(void* const* d_in, const int* in_sizes, int n_in,
                              void* d_out, int out_size, void* d_ws, size_t ws_size,
                              hipStream_t stream) {
    const float* H_src    = (const float*)d_in[0];
    const float* H_dst    = (const float*)d_in[1];
    const float* HBar_src = (const float*)d_in[2];
    const float* agg      = (const float*)d_in[3];
    const float* W        = (const float*)d_in[4];
    const float* bias     = (const float*)d_in[5];
    const int*   src      = (const int*)d_in[6];
    const int*   dst      = (const int*)d_in[7];
    float* out = (float*)d_out;
    const int E = in_sizes[6];
    const int NB = (NDST + 255) / 256;   // 196

    // ws layout (byte offsets, 512-aligned):
    //   cnt    : 0         .. 200,000
    //   cnt2   : 200,192   .. 400,192
    //   off    : 400,384   .. 600,388   (NDST+1)
    //   bsum   : 600,576   .. 601,360   (196 i32)
    //   bexcl  : 601,600   .. 602,384
    //   idx    : 602,624   .. 3,802,624 (E i32)
    //   WT     : 3,803,136 .. 3,868,672 (128*256 bf16)
    //   hd_bf  : 3,868,672 .. 29,468,672 (NSRC*128 bf16)
    char* ws = (char*)d_ws;
    int* cnt             = (int*)ws;
    int* cnt2            = (int*)(ws + 200192);
    int* off             = (int*)(ws + 400384);
    int* bsum            = (int*)(ws + 600576);
    int* bexcl           = (int*)(ws + 601600);
    int* idx_sorted      = (int*)(ws + 602624);
    unsigned short* WT   = (unsigned short*)(ws + 3803136);
    unsigned short* hdbf = (unsigned short*)(ws + 3868672);

    k_prep<<<NB, 256, 0, stream>>>(W, WT, cnt, cnt2);

    int n4 = NSRC * 32;
    k_hd_hist<<<(n4 + 255) / 256, 256, 0, stream>>>(
        (const float4*)H_src, (const float4*)HBar_src, (ushort4*)hdbf,
        dst, cnt, E, n4);

    k_scan1<<<NB, 256, 0, stream>>>(cnt, bsum, NDST);
    k_scan2<<<1, 256, 0, stream>>>(bsum, bexcl, off + NDST, NB);
    k_scan3<<<NB, 256, 0, stream>>>(cnt, bexcl, off, NDST);

    k_scatter<<<(E + 255) / 256, 256, 0, stream>>>(src, dst, off, cnt2, idx_sorted, E);

    k_fused<<<NDST / 16, 256, 0, stream>>>(
        (const uint32_t*)hdbf, (const float2*)H_dst, (const float2*)agg,
        off, idx_sorted, WT, bias, out);
}